// Round 1
// baseline (1257.140 us; speedup 1.0000x reference)
//
#include <hip/hip_runtime.h>
#include <hip/hip_bf16.h>

#define F_DIM 128
#define N_RBF 20
#define CUTOFF 5.0f
#define PI_F 3.14159265358979323846f

// ---------------------------------------------------------------------------
// row_ptr[i] = lower_bound(idx_i, i)  (idx_i is sorted)
__global__ __launch_bounds__(256) void k_rowptr(const int* __restrict__ idx_i,
                                                int* __restrict__ row_ptr, int N, int E) {
    int i = blockIdx.x * blockDim.x + threadIdx.x;
    if (i > N) return;
    if (i == N) { row_ptr[N] = E; return; }
    int lo = 0, hi = E;
    while (lo < hi) {
        int mid = (lo + hi) >> 1;
        if (idx_i[mid] < i) lo = mid + 1; else hi = mid;
    }
    row_ptr[i] = lo;
}

// ---------------------------------------------------------------------------
// q = embedding[Z], muA = 0
__global__ __launch_bounds__(256) void k_init(const int* __restrict__ Z,
                                              const float* __restrict__ emb,
                                              float* __restrict__ q,
                                              float* __restrict__ muA, int N) {
    int idx = blockIdx.x * blockDim.x + threadIdx.x;
    if (idx < N * F_DIM) {
        int n = idx >> 7, f = idx & 127;
        q[idx] = emb[Z[n] * F_DIM + f];
    }
    if (idx < N * 3 * F_DIM) muA[idx] = 0.f;
}

// ---------------------------------------------------------------------------
// Per-edge geometry record (24 floats): dir(3), fcut(1), phi*fcut(20)
__global__ __launch_bounds__(256) void k_geom(const float* __restrict__ r,
                                              float* __restrict__ geom, int E) {
    int e = blockIdx.x * blockDim.x + threadIdx.x;
    if (e >= E) return;
    float x = r[e * 3], y = r[e * 3 + 1], z = r[e * 3 + 2];
    float d = sqrtf(x * x + y * y + z * z);
    float inv = 1.f / d;
    float fc = (d < CUTOFF) ? 0.5f * (__cosf(d * (PI_F / CUTOFF)) + 1.f) : 0.f;
    float* g = geom + (size_t)e * 24;
    g[0] = x * inv; g[1] = y * inv; g[2] = z * inv; g[3] = fc;
    const float delta = CUTOFF / (N_RBF - 1);
    const float coeff = -0.5f / (delta * delta);
#pragma unroll
    for (int k = 0; k < N_RBF; k++) {
        float t = d - k * delta;
        g[4 + k] = __expf(coeff * t * t) * fc;
    }
}

// ---------------------------------------------------------------------------
// x = silu(q@W1 + b1)@W2 + b2     16 nodes / block, 256 threads
__global__ __launch_bounds__(256) void k_node_msg(const float* __restrict__ q,
                                                  const float* __restrict__ W1,
                                                  const float* __restrict__ b1,
                                                  const float* __restrict__ W2,
                                                  const float* __restrict__ b2,
                                                  float* __restrict__ x, int N) {
    __shared__ float qs[16][128];
    __shared__ float hs[16][128];
    int n0 = blockIdx.x * 16;
    int t = threadIdx.x;
    int f = t & 127, nb = t >> 7;

    for (int r = 0; r < 8; r++) {
        int idx = r * 256 + t;
        int n = idx >> 7, ff = idx & 127;
        int gn = n0 + n;
        qs[n][ff] = (gn < N) ? q[(size_t)gn * 128 + ff] : 0.f;
    }
    __syncthreads();

    {   // h = silu(q@W1 + b1)
        float acc[8];
#pragma unroll
        for (int r = 0; r < 8; r++) acc[r] = b1[f];
        for (int k = 0; k < 128; k++) {
            float w = W1[k * 128 + f];
#pragma unroll
            for (int r = 0; r < 8; r++) acc[r] += qs[2 * r + nb][k] * w;
        }
#pragma unroll
        for (int r = 0; r < 8; r++) {
            float a = acc[r];
            hs[2 * r + nb][f] = a / (1.f + __expf(-a));
        }
    }
    __syncthreads();

    {   // x = h@W2 + b2   (W2 cols as 3 chunks of 128)
        float x0[8], x1[8], x2[8];
#pragma unroll
        for (int r = 0; r < 8; r++) { x0[r] = b2[f]; x1[r] = b2[128 + f]; x2[r] = b2[256 + f]; }
        for (int k = 0; k < 128; k++) {
            float w0 = W2[k * 384 + f];
            float w1 = W2[k * 384 + 128 + f];
            float w2 = W2[k * 384 + 256 + f];
#pragma unroll
            for (int r = 0; r < 8; r++) {
                float h = hs[2 * r + nb][k];
                x0[r] += h * w0; x1[r] += h * w1; x2[r] += h * w2;
            }
        }
#pragma unroll
        for (int r = 0; r < 8; r++) {
            int gn = n0 + 2 * r + nb;
            if (gn < N) {
                size_t base = (size_t)gn * 384;
                x[base + f] = x0[r];
                x[base + 128 + f] = x1[r];
                x[base + 256 + f] = x2[r];
            }
        }
    }
}

// ---------------------------------------------------------------------------
// Edge aggregation: one block per destination node i (CSR). 256 threads:
// 2 edge "lanes" (sub = t>>7) x 128 features. Filters recomputed from
// phi*fcut (geom) with filt_W layer slice staged in LDS.
__global__ __launch_bounds__(256) void k_edge(const float* __restrict__ x,
                                              const float* __restrict__ mu_in,
                                              const float* __restrict__ geom,
                                              const int* __restrict__ idx_j,
                                              const int* __restrict__ row_ptr,
                                              const float* __restrict__ filt_W,
                                              const float* __restrict__ filt_b,
                                              int layer,
                                              float* __restrict__ q,
                                              float* __restrict__ mu_out, int N) {
    __shared__ float Wf[20][384];
    __shared__ float bf[384];
    __shared__ float red[4][128];
    int i = blockIdx.x;
    int t = threadIdx.x;

    for (int idx = t; idx < 20 * 384; idx += 256) {
        int k = idx / 384, c = idx % 384;
        Wf[k][c] = filt_W[k * 1152 + layer * 384 + c];
    }
    for (int c = t; c < 384; c += 256) bf[c] = filt_b[layer * 384 + c];
    __syncthreads();

    int rs = row_ptr[i], re = row_ptr[i + 1];
    int f = t & 127, sub = t >> 7;
    float dq = 0.f, dm0 = 0.f, dm1 = 0.f, dm2 = 0.f;

    for (int e = rs + sub; e < re; e += 2) {
        const float* g = geom + (size_t)e * 24;
        float dirx = g[0], diry = g[1], dirz = g[2], fc = g[3];
        int j = idx_j[e];
        float wq = fc * bf[f];
        float wr = fc * bf[128 + f];
        float wm = fc * bf[256 + f];
#pragma unroll
        for (int k = 0; k < 20; k++) {
            float p = g[4 + k];
            wq += p * Wf[k][f];
            wr += p * Wf[k][128 + f];
            wm += p * Wf[k][256 + f];
        }
        const float* xj = x + (size_t)j * 384;
        const float* mj = mu_in + (size_t)j * 384;
        float s_q = wq * xj[f];
        float s_r = wr * xj[128 + f];
        float s_m = wm * xj[256 + f];
        dq += s_q;
        dm0 += s_r * dirx + s_m * mj[f];
        dm1 += s_r * diry + s_m * mj[128 + f];
        dm2 += s_r * dirz + s_m * mj[256 + f];
    }

    if (sub == 1) { red[0][f] = dq; red[1][f] = dm0; red[2][f] = dm1; red[3][f] = dm2; }
    __syncthreads();
    if (sub == 0) {
        dq += red[0][f]; dm0 += red[1][f]; dm1 += red[2][f]; dm2 += red[3][f];
        q[(size_t)i * 128 + f] += dq;
        size_t base = (size_t)i * 384;
        mu_out[base + f]       = mu_in[base + f] + dm0;
        mu_out[base + 128 + f] = mu_in[base + 128 + f] + dm1;
        mu_out[base + 256 + f] = mu_in[base + 256 + f] + dm2;
    }
}

// ---------------------------------------------------------------------------
// Mixing block: 8 nodes / block, 256 threads. In-place update of q, mu.
__global__ __launch_bounds__(256) void k_mix(float* __restrict__ q,
                                             float* __restrict__ mu,
                                             const float* __restrict__ muxW,
                                             const float* __restrict__ W1,
                                             const float* __restrict__ b1,
                                             const float* __restrict__ W2,
                                             const float* __restrict__ b2, int N) {
    __shared__ float mus[8][3][128];
    __shared__ float qs[8][128];
    __shared__ float Vs[8][3][128];
    __shared__ float Ws_[8][3][128];
    __shared__ float vns[8][128];
    __shared__ float hs[8][128];
    int n0 = blockIdx.x * 8;
    int t = threadIdx.x;
    int f = t & 127, nb = t >> 7;

    for (int idx = t; idx < 3072; idx += 256) {
        int n = idx / 384, rem = idx % 384;
        int gn = n0 + n;
        ((float*)mus)[idx] = (gn < N) ? mu[(size_t)gn * 384 + rem] : 0.f;
    }
    for (int idx = t; idx < 1024; idx += 256) {
        int n = idx >> 7, ff = idx & 127;
        int gn = n0 + n;
        qs[n][ff] = (gn < N) ? q[(size_t)gn * 128 + ff] : 0.f;
    }
    __syncthreads();

    {   // mu_mix = mu @ muxW : half nb==0 computes V cols, nb==1 the W cols
        float acc[8][3];
#pragma unroll
        for (int n = 0; n < 8; n++)
#pragma unroll
            for (int c = 0; c < 3; c++) acc[n][c] = 0.f;
        for (int k = 0; k < 128; k++) {
            float w = muxW[k * 256 + nb * 128 + f];
#pragma unroll
            for (int n = 0; n < 8; n++) {
                acc[n][0] += mus[n][0][k] * w;
                acc[n][1] += mus[n][1][k] * w;
                acc[n][2] += mus[n][2][k] * w;
            }
        }
        if (nb == 0) {
#pragma unroll
            for (int n = 0; n < 8; n++)
#pragma unroll
                for (int c = 0; c < 3; c++) Vs[n][c][f] = acc[n][c];
        } else {
#pragma unroll
            for (int n = 0; n < 8; n++)
#pragma unroll
                for (int c = 0; c < 3; c++) Ws_[n][c][f] = acc[n][c];
        }
    }
    __syncthreads();

    for (int idx = t; idx < 1024; idx += 256) {
        int n = idx >> 7, ff = idx & 127;
        float v0 = Vs[n][0][ff], v1 = Vs[n][1][ff], v2 = Vs[n][2][ff];
        vns[n][ff] = sqrtf(v0 * v0 + v1 * v1 + v2 * v2 + 1e-8f);
    }
    __syncthreads();

    {   // h = silu([q, vn] @ W1 + b1)
        float acc[4];
#pragma unroll
        for (int r = 0; r < 4; r++) acc[r] = b1[f];
        for (int k = 0; k < 128; k++) {
            float w = W1[k * 128 + f];
#pragma unroll
            for (int r = 0; r < 4; r++) acc[r] += qs[2 * r + nb][k] * w;
        }
        for (int k = 0; k < 128; k++) {
            float w = W1[(128 + k) * 128 + f];
#pragma unroll
            for (int r = 0; r < 4; r++) acc[r] += vns[2 * r + nb][k] * w;
        }
#pragma unroll
        for (int r = 0; r < 4; r++) {
            float a = acc[r];
            hs[2 * r + nb][f] = a / (1.f + __expf(-a));
        }
    }
    __syncthreads();

    {   // x = h @ W2 + b2 ; then update q, mu
        float x0[4], x1[4], x2[4];
#pragma unroll
        for (int r = 0; r < 4; r++) { x0[r] = b2[f]; x1[r] = b2[128 + f]; x2[r] = b2[256 + f]; }
        for (int k = 0; k < 128; k++) {
            float w0 = W2[k * 384 + f];
            float w1 = W2[k * 384 + 128 + f];
            float w2 = W2[k * 384 + 256 + f];
#pragma unroll
            for (int r = 0; r < 4; r++) {
                float h = hs[2 * r + nb][k];
                x0[r] += h * w0; x1[r] += h * w1; x2[r] += h * w2;
            }
        }
#pragma unroll
        for (int r = 0; r < 4; r++) {
            int n = 2 * r + nb;
            int gn = n0 + n;
            if (gn >= N) continue;
            float S = Vs[n][0][f] * Ws_[n][0][f] + Vs[n][1][f] * Ws_[n][1][f] +
                      Vs[n][2][f] * Ws_[n][2][f];
            q[(size_t)gn * 128 + f] = qs[n][f] + x0[r] + x2[r] * S;
            size_t base = (size_t)gn * 384;
#pragma unroll
            for (int c = 0; c < 3; c++)
                mu[base + c * 128 + f] = mus[n][c][f] + x1[r] * Ws_[n][c][f];
        }
    }
}

// ---------------------------------------------------------------------------
extern "C" void kernel_launch(void* const* d_in, const int* in_sizes, int n_in,
                              void* d_out, int out_size, void* d_ws, size_t ws_size,
                              hipStream_t stream) {
    const int*   Z      = (const int*)d_in[0];
    const float* r_ij   = (const float*)d_in[1];
    const int*   idx_i  = (const int*)d_in[2];
    const int*   idx_j  = (const int*)d_in[3];
    const float* emb    = (const float*)d_in[4];
    const float* filt_W = (const float*)d_in[5];
    const float* filt_b = (const float*)d_in[6];
    const float* int_W1 = (const float*)d_in[7];
    const float* int_b1 = (const float*)d_in[8];
    const float* int_W2 = (const float*)d_in[9];
    const float* int_b2 = (const float*)d_in[10];
    const float* mix_W1 = (const float*)d_in[11];
    const float* mix_b1 = (const float*)d_in[12];
    const float* mix_W2 = (const float*)d_in[13];
    const float* mix_b2 = (const float*)d_in[14];
    const float* mux_W  = (const float*)d_in[15];

    int N = in_sizes[0];
    int E = in_sizes[2];

    float* q   = (float*)d_out;              // [N,128]
    float* muD = q + (size_t)N * 128;        // [N,3,128]  (final mu lives here)

    float* ws   = (float*)d_ws;
    float* geom = ws;                          // E*24
    float* xbuf = geom + (size_t)E * 24;       // N*384
    float* muA  = xbuf + (size_t)N * 384;      // N*384
    int* row_ptr = (int*)(muA + (size_t)N * 384);  // N+1

    k_rowptr<<<(N + 1 + 255) / 256, 256, 0, stream>>>(idx_i, row_ptr, N, E);
    k_init<<<((size_t)N * 384 + 255) / 256, 256, 0, stream>>>(Z, emb, q, muA, N);
    k_geom<<<(E + 255) / 256, 256, 0, stream>>>(r_ij, geom, E);

    float* mu_in = muA;
    float* mu_out = muD;
    for (int l = 0; l < 3; l++) {
        k_node_msg<<<(N + 15) / 16, 256, 0, stream>>>(
            q, int_W1 + (size_t)l * 128 * 128, int_b1 + l * 128,
            int_W2 + (size_t)l * 128 * 384, int_b2 + l * 384, xbuf, N);
        k_edge<<<N, 256, 0, stream>>>(xbuf, mu_in, geom, idx_j, row_ptr,
                                      filt_W, filt_b, l, q, mu_out, N);
        k_mix<<<(N + 7) / 8, 256, 0, stream>>>(
            q, mu_out, mux_W + (size_t)l * 128 * 256,
            mix_W1 + (size_t)l * 256 * 128, mix_b1 + l * 128,
            mix_W2 + (size_t)l * 128 * 384, mix_b2 + l * 384, N);
        float* tmp = mu_in; mu_in = mu_out; mu_out = tmp;
    }
    // after 3 swaps: layer-2 output (mu) is in muD == d_out mu region; q in d_out.
}

// Round 2
// 1184.766 us; speedup vs baseline: 1.0611x; 1.0611x over previous
//
#include <hip/hip_runtime.h>
#include <hip/hip_bf16.h>

#define F_DIM 128
#define N_RBF 20
#define CUTOFF 5.0f
#define PI_F 3.14159265358979323846f

// ---------------------------------------------------------------------------
// row_ptr[i] = lower_bound(idx_i, i)  (idx_i is sorted)
__global__ __launch_bounds__(256) void k_rowptr(const int* __restrict__ idx_i,
                                                int* __restrict__ row_ptr, int N, int E) {
    int i = blockIdx.x * blockDim.x + threadIdx.x;
    if (i > N) return;
    if (i == N) { row_ptr[N] = E; return; }
    int lo = 0, hi = E;
    while (lo < hi) {
        int mid = (lo + hi) >> 1;
        if (idx_i[mid] < i) lo = mid + 1; else hi = mid;
    }
    row_ptr[i] = lo;
}

// ---------------------------------------------------------------------------
// q = embedding[Z], muA = 0
__global__ __launch_bounds__(256) void k_init(const int* __restrict__ Z,
                                              const float* __restrict__ emb,
                                              float* __restrict__ q,
                                              float* __restrict__ muA, int N) {
    int idx = blockIdx.x * blockDim.x + threadIdx.x;
    if (idx < N * F_DIM) {
        int n = idx >> 7, f = idx & 127;
        q[idx] = emb[Z[n] * F_DIM + f];
    }
    if (idx < N * 3 * F_DIM) muA[idx] = 0.f;
}

// ---------------------------------------------------------------------------
// Per-edge geometry record (24 floats): dir(3), fcut(1), phi*fcut(20)
__global__ __launch_bounds__(256) void k_geom(const float* __restrict__ r,
                                              float* __restrict__ geom, int E) {
    int e = blockIdx.x * blockDim.x + threadIdx.x;
    if (e >= E) return;
    float x = r[e * 3], y = r[e * 3 + 1], z = r[e * 3 + 2];
    float d = sqrtf(x * x + y * y + z * z);
    float inv = 1.f / d;
    float fc = (d < CUTOFF) ? 0.5f * (__cosf(d * (PI_F / CUTOFF)) + 1.f) : 0.f;
    float* g = geom + (size_t)e * 24;
    g[0] = x * inv; g[1] = y * inv; g[2] = z * inv; g[3] = fc;
    const float delta = CUTOFF / (N_RBF - 1);
    const float coeff = -0.5f / (delta * delta);
#pragma unroll
    for (int k = 0; k < N_RBF; k++) {
        float t = d - k * delta;
        g[4 + k] = __expf(coeff * t * t) * fc;
    }
}

// ---------------------------------------------------------------------------
// x = silu(q@W1 + b1)@W2 + b2     16 nodes / block, 256 threads
__global__ __launch_bounds__(256) void k_node_msg(const float* __restrict__ q,
                                                  const float* __restrict__ W1,
                                                  const float* __restrict__ b1,
                                                  const float* __restrict__ W2,
                                                  const float* __restrict__ b2,
                                                  float* __restrict__ x, int N) {
    __shared__ float qs[16][128];
    __shared__ float hs[16][128];
    int n0 = blockIdx.x * 16;
    int t = threadIdx.x;
    int f = t & 127, nb = t >> 7;

    for (int r = 0; r < 8; r++) {
        int idx = r * 256 + t;
        int n = idx >> 7, ff = idx & 127;
        int gn = n0 + n;
        qs[n][ff] = (gn < N) ? q[(size_t)gn * 128 + ff] : 0.f;
    }
    __syncthreads();

    {   // h = silu(q@W1 + b1)
        float acc[8];
#pragma unroll
        for (int r = 0; r < 8; r++) acc[r] = b1[f];
        for (int k = 0; k < 128; k++) {
            float w = W1[k * 128 + f];
#pragma unroll
            for (int r = 0; r < 8; r++) acc[r] += qs[2 * r + nb][k] * w;
        }
#pragma unroll
        for (int r = 0; r < 8; r++) {
            float a = acc[r];
            hs[2 * r + nb][f] = a / (1.f + __expf(-a));
        }
    }
    __syncthreads();

    {   // x = h@W2 + b2   (W2 cols as 3 chunks of 128)
        float x0[8], x1[8], x2[8];
#pragma unroll
        for (int r = 0; r < 8; r++) { x0[r] = b2[f]; x1[r] = b2[128 + f]; x2[r] = b2[256 + f]; }
        for (int k = 0; k < 128; k++) {
            float w0 = W2[k * 384 + f];
            float w1 = W2[k * 384 + 128 + f];
            float w2 = W2[k * 384 + 256 + f];
#pragma unroll
            for (int r = 0; r < 8; r++) {
                float h = hs[2 * r + nb][k];
                x0[r] += h * w0; x1[r] += h * w1; x2[r] += h * w2;
            }
        }
#pragma unroll
        for (int r = 0; r < 8; r++) {
            int gn = n0 + 2 * r + nb;
            if (gn < N) {
                size_t base = (size_t)gn * 384;
                x[base + f] = x0[r];
                x[base + 128 + f] = x1[r];
                x[base + 256 + f] = x2[r];
            }
        }
    }
}

// ---------------------------------------------------------------------------
// Edge aggregation: one block per destination node i (CSR). 256 threads:
// 2 edge "lanes" (sub = t>>7) x 128 features. Filter weights for this
// thread's 3 feature columns live in REGISTERS (fixed across edges):
// 60 VGPRs of Wf + 3 of bf. No LDS except the 2KB reduction buffer.
__global__ __launch_bounds__(256) void k_edge(const float* __restrict__ x,
                                              const float* __restrict__ mu_in,
                                              const float* __restrict__ geom,
                                              const int* __restrict__ idx_j,
                                              const int* __restrict__ row_ptr,
                                              const float* __restrict__ filt_W,
                                              const float* __restrict__ filt_b,
                                              int layer,
                                              float* __restrict__ q,
                                              float* __restrict__ mu_out, int N) {
    __shared__ float red[4][128];
    int i = blockIdx.x;
    int t = threadIdx.x;
    int f = t & 127, sub = t >> 7;

    // Per-thread filter weights in registers
    float Wfr0[N_RBF], Wfr1[N_RBF], Wfr2[N_RBF];
    const float* Wbase = filt_W + layer * 384;
#pragma unroll
    for (int k = 0; k < N_RBF; k++) {
        Wfr0[k] = Wbase[k * 1152 + f];
        Wfr1[k] = Wbase[k * 1152 + 128 + f];
        Wfr2[k] = Wbase[k * 1152 + 256 + f];
    }
    float bf0 = filt_b[layer * 384 + f];
    float bf1 = filt_b[layer * 384 + 128 + f];
    float bf2 = filt_b[layer * 384 + 256 + f];

    int rs = row_ptr[i], re = row_ptr[i + 1];
    float dq = 0.f, dm0 = 0.f, dm1 = 0.f, dm2 = 0.f;

    for (int e = rs + sub; e < re; e += 2) {
        const float4* g4 = (const float4*)(geom + (size_t)e * 24);
        float4 a  = g4[0];                 // dirx, diry, dirz, fcut
        float4 p0 = g4[1], p1 = g4[2], p2 = g4[3], p3 = g4[4], p4 = g4[5];
        int j = idx_j[e];
        const float* xj = x + (size_t)j * 384;
        const float* mj = mu_in + (size_t)j * 384;
        float xq = xj[f], xr = xj[128 + f], xm = xj[256 + f];
        float m0 = mj[f], m1 = mj[128 + f], m2 = mj[256 + f];

        float wq = a.w * bf0, wr = a.w * bf1, wm = a.w * bf2;
        float ph[N_RBF] = {p0.x, p0.y, p0.z, p0.w, p1.x, p1.y, p1.z, p1.w,
                           p2.x, p2.y, p2.z, p2.w, p3.x, p3.y, p3.z, p3.w,
                           p4.x, p4.y, p4.z, p4.w};
#pragma unroll
        for (int k = 0; k < N_RBF; k++) {
            wq += ph[k] * Wfr0[k];
            wr += ph[k] * Wfr1[k];
            wm += ph[k] * Wfr2[k];
        }
        float s_q = wq * xq;
        float s_r = wr * xr;
        float s_m = wm * xm;
        dq  += s_q;
        dm0 += s_r * a.x + s_m * m0;
        dm1 += s_r * a.y + s_m * m1;
        dm2 += s_r * a.z + s_m * m2;
    }

    if (sub == 1) { red[0][f] = dq; red[1][f] = dm0; red[2][f] = dm1; red[3][f] = dm2; }
    __syncthreads();
    if (sub == 0) {
        dq += red[0][f]; dm0 += red[1][f]; dm1 += red[2][f]; dm2 += red[3][f];
        q[(size_t)i * 128 + f] += dq;
        size_t base = (size_t)i * 384;
        mu_out[base + f]       = mu_in[base + f] + dm0;
        mu_out[base + 128 + f] = mu_in[base + 128 + f] + dm1;
        mu_out[base + 256 + f] = mu_in[base + 256 + f] + dm2;
    }
}

// ---------------------------------------------------------------------------
// Mixing block: 8 nodes / block, 256 threads. In-place update of q, mu.
__global__ __launch_bounds__(256) void k_mix(float* __restrict__ q,
                                             float* __restrict__ mu,
                                             const float* __restrict__ muxW,
                                             const float* __restrict__ W1,
                                             const float* __restrict__ b1,
                                             const float* __restrict__ W2,
                                             const float* __restrict__ b2, int N) {
    __shared__ float mus[8][3][128];
    __shared__ float qs[8][128];
    __shared__ float Vs[8][3][128];
    __shared__ float Ws_[8][3][128];
    __shared__ float vns[8][128];
    __shared__ float hs[8][128];
    int n0 = blockIdx.x * 8;
    int t = threadIdx.x;
    int f = t & 127, nb = t >> 7;

    for (int idx = t; idx < 3072; idx += 256) {
        int n = idx / 384, rem = idx % 384;
        int gn = n0 + n;
        ((float*)mus)[idx] = (gn < N) ? mu[(size_t)gn * 384 + rem] : 0.f;
    }
    for (int idx = t; idx < 1024; idx += 256) {
        int n = idx >> 7, ff = idx & 127;
        int gn = n0 + n;
        qs[n][ff] = (gn < N) ? q[(size_t)gn * 128 + ff] : 0.f;
    }
    __syncthreads();

    {   // mu_mix = mu @ muxW : half nb==0 computes V cols, nb==1 the W cols
        float acc[8][3];
#pragma unroll
        for (int n = 0; n < 8; n++)
#pragma unroll
            for (int c = 0; c < 3; c++) acc[n][c] = 0.f;
        for (int k = 0; k < 128; k++) {
            float w = muxW[k * 256 + nb * 128 + f];
#pragma unroll
            for (int n = 0; n < 8; n++) {
                acc[n][0] += mus[n][0][k] * w;
                acc[n][1] += mus[n][1][k] * w;
                acc[n][2] += mus[n][2][k] * w;
            }
        }
        if (nb == 0) {
#pragma unroll
            for (int n = 0; n < 8; n++)
#pragma unroll
                for (int c = 0; c < 3; c++) Vs[n][c][f] = acc[n][c];
        } else {
#pragma unroll
            for (int n = 0; n < 8; n++)
#pragma unroll
                for (int c = 0; c < 3; c++) Ws_[n][c][f] = acc[n][c];
        }
    }
    __syncthreads();

    for (int idx = t; idx < 1024; idx += 256) {
        int n = idx >> 7, ff = idx & 127;
        float v0 = Vs[n][0][ff], v1 = Vs[n][1][ff], v2 = Vs[n][2][ff];
        vns[n][ff] = sqrtf(v0 * v0 + v1 * v1 + v2 * v2 + 1e-8f);
    }
    __syncthreads();

    {   // h = silu([q, vn] @ W1 + b1)
        float acc[4];
#pragma unroll
        for (int r = 0; r < 4; r++) acc[r] = b1[f];
        for (int k = 0; k < 128; k++) {
            float w = W1[k * 128 + f];
#pragma unroll
            for (int r = 0; r < 4; r++) acc[r] += qs[2 * r + nb][k] * w;
        }
        for (int k = 0; k < 128; k++) {
            float w = W1[(128 + k) * 128 + f];
#pragma unroll
            for (int r = 0; r < 4; r++) acc[r] += vns[2 * r + nb][k] * w;
        }
#pragma unroll
        for (int r = 0; r < 4; r++) {
            float a = acc[r];
            hs[2 * r + nb][f] = a / (1.f + __expf(-a));
        }
    }
    __syncthreads();

    {   // x = h @ W2 + b2 ; then update q, mu
        float x0[4], x1[4], x2[4];
#pragma unroll
        for (int r = 0; r < 4; r++) { x0[r] = b2[f]; x1[r] = b2[128 + f]; x2[r] = b2[256 + f]; }
        for (int k = 0; k < 128; k++) {
            float w0 = W2[k * 384 + f];
            float w1 = W2[k * 384 + 128 + f];
            float w2 = W2[k * 384 + 256 + f];
#pragma unroll
            for (int r = 0; r < 4; r++) {
                float h = hs[2 * r + nb][k];
                x0[r] += h * w0; x1[r] += h * w1; x2[r] += h * w2;
            }
        }
#pragma unroll
        for (int r = 0; r < 4; r++) {
            int n = 2 * r + nb;
            int gn = n0 + n;
            if (gn >= N) continue;
            float S = Vs[n][0][f] * Ws_[n][0][f] + Vs[n][1][f] * Ws_[n][1][f] +
                      Vs[n][2][f] * Ws_[n][2][f];
            q[(size_t)gn * 128 + f] = qs[n][f] + x0[r] + x2[r] * S;
            size_t base = (size_t)gn * 384;
#pragma unroll
            for (int c = 0; c < 3; c++)
                mu[base + c * 128 + f] = mus[n][c][f] + x1[r] * Ws_[n][c][f];
        }
    }
}

// ---------------------------------------------------------------------------
extern "C" void kernel_launch(void* const* d_in, const int* in_sizes, int n_in,
                              void* d_out, int out_size, void* d_ws, size_t ws_size,
                              hipStream_t stream) {
    const int*   Z      = (const int*)d_in[0];
    const float* r_ij   = (const float*)d_in[1];
    const int*   idx_i  = (const int*)d_in[2];
    const int*   idx_j  = (const int*)d_in[3];
    const float* emb    = (const float*)d_in[4];
    const float* filt_W = (const float*)d_in[5];
    const float* filt_b = (const float*)d_in[6];
    const float* int_W1 = (const float*)d_in[7];
    const float* int_b1 = (const float*)d_in[8];
    const float* int_W2 = (const float*)d_in[9];
    const float* int_b2 = (const float*)d_in[10];
    const float* mix_W1 = (const float*)d_in[11];
    const float* mix_b1 = (const float*)d_in[12];
    const float* mix_W2 = (const float*)d_in[13];
    const float* mix_b2 = (const float*)d_in[14];
    const float* mux_W  = (const float*)d_in[15];

    int N = in_sizes[0];
    int E = in_sizes[2];

    float* q   = (float*)d_out;              // [N,128]
    float* muD = q + (size_t)N * 128;        // [N,3,128]  (final mu lives here)

    float* ws   = (float*)d_ws;
    float* geom = ws;                          // E*24
    float* xbuf = geom + (size_t)E * 24;       // N*384
    float* muA  = xbuf + (size_t)N * 384;      // N*384
    int* row_ptr = (int*)(muA + (size_t)N * 384);  // N+1

    k_rowptr<<<(N + 1 + 255) / 256, 256, 0, stream>>>(idx_i, row_ptr, N, E);
    k_init<<<((size_t)N * 384 + 255) / 256, 256, 0, stream>>>(Z, emb, q, muA, N);
    k_geom<<<(E + 255) / 256, 256, 0, stream>>>(r_ij, geom, E);

    float* mu_in = muA;
    float* mu_out = muD;
    for (int l = 0; l < 3; l++) {
        k_node_msg<<<(N + 15) / 16, 256, 0, stream>>>(
            q, int_W1 + (size_t)l * 128 * 128, int_b1 + l * 128,
            int_W2 + (size_t)l * 128 * 384, int_b2 + l * 384, xbuf, N);
        k_edge<<<N, 256, 0, stream>>>(xbuf, mu_in, geom, idx_j, row_ptr,
                                      filt_W, filt_b, l, q, mu_out, N);
        k_mix<<<(N + 7) / 8, 256, 0, stream>>>(
            q, mu_out, mux_W + (size_t)l * 128 * 256,
            mix_W1 + (size_t)l * 256 * 128, mix_b1 + l * 128,
            mix_W2 + (size_t)l * 128 * 384, mix_b2 + l * 384, N);
        float* tmp = mu_in; mu_in = mu_out; mu_out = tmp;
    }
    // after 3 swaps: layer-2 output (mu) is in muD == d_out mu region; q in d_out.
}